// Round 13
// baseline (389.780 us; speedup 1.0000x reference)
//
#include <hip/hip_runtime.h>
#include <hip/hip_fp16.h>
#include <math.h>

#define D 128
#define ED 10
#define FF 512
#define TPAD 520   // bf16 per LDS row in ffn t-tile (512 + 8 pad)
#define XPAD 136   // bf16 per LDS row for 128-wide tiles (128 + 8 pad)

typedef __attribute__((ext_vector_type(4))) float f32x4;
typedef __attribute__((ext_vector_type(8))) short bf16x8;
using h2 = decltype(__builtin_amdgcn_cvt_pkrtz(0.f, 0.f));  // __fp16 ext_vector(2)
typedef __attribute__((ext_vector_type(2))) float f32x2;

__device__ __forceinline__ ushort f2bf(float f) {
  unsigned u = __float_as_uint(f);
  unsigned r = u + 0x7fffu + ((u >> 16) & 1u);
  return (ushort)(r >> 16);
}
__device__ __forceinline__ float bf2f(ushort u) {
  return __uint_as_float(((unsigned)u) << 16);
}

// in-quad butterfly add via DPP (VALU pipe): 0xB1 = xor1, 0x4E = xor2
__device__ __forceinline__ float dpp_add_xor1(float x) {
  int y = __builtin_amdgcn_update_dpp(0, __builtin_bit_cast(int, x), 0xB1, 0xF, 0xF, true);
  return x + __builtin_bit_cast(float, y);
}
__device__ __forceinline__ float dpp_add_xor2(float x) {
  int y = __builtin_amdgcn_update_dpp(0, __builtin_bit_cast(int, x), 0x4E, 0xF, 0xF, true);
  return x + __builtin_bit_cast(float, y);
}

// ---- fp8 e4m3 pack/unpack ----
#if __has_builtin(__builtin_amdgcn_cvt_pk_f32_fp8) && __has_builtin(__builtin_amdgcn_cvt_pk_fp8_f32)
#define FP8_HW 1
#else
#define FP8_HW 0
#endif

__device__ __forceinline__ unsigned sw_f2fp8(float f) {
  unsigned u = __float_as_uint(f);
  unsigned s = (u >> 24) & 0x80;
  int e = (int)((u >> 23) & 0xff) - 127;
  unsigned mant = u & 0x7fffff;
  if (e < -9) return s;
  if (e > 8) return s | 0x7e;
  if (e >= -6) {
    unsigned m = mant + 0x7ffff + ((mant >> 20) & 1);
    if (m >= 0x800000) { m = 0; ++e; if (e > 8) return s | 0x7e; }
    return s | ((unsigned)(e + 7) << 3) | (m >> 20);
  }
  unsigned full = 0x800000 | mant;
  int shift = 20 + (-6 - e);
  unsigned m = (full + (1u << (shift - 1)) + ((full >> shift) & 1)) >> shift;
  if (m >= 8) return s | 0x08;
  return s | m;
}
__device__ __forceinline__ float sw_fp82f(unsigned b) {
  unsigned s = (b & 0x80) << 24;
  unsigned e = (b >> 3) & 0xf;
  unsigned m = b & 7;
  if (e == 0) {
    if (m == 0) return __uint_as_float(s);
    float v = (float)(int)m * 0.001953125f;
    return (b & 0x80) ? -v : v;
  }
  return __uint_as_float(s | ((e + 120) << 23) | (m << 20));
}

__device__ __forceinline__ ushort pack_fp8_pair(float a, float b) {
#if FP8_HW
  int r = __builtin_amdgcn_cvt_pk_fp8_f32(a, b, 0, false);
  return (ushort)(r & 0xffff);
#else
  return (ushort)(sw_f2fp8(a) | (sw_f2fp8(b) << 8));
#endif
}
template <bool HI>
__device__ __forceinline__ f32x2 unpack_fp8_pair(unsigned w) {
#if FP8_HW
  auto r = __builtin_amdgcn_cvt_pk_f32_fp8((int)w, HI);
  f32x2 o; o[0] = r[0]; o[1] = r[1];
  return o;
#else
  unsigned v = HI ? (w >> 16) : w;
  f32x2 o; o[0] = sw_fp82f(v & 0xff); o[1] = sw_fp82f((v >> 8) & 0xff);
  return o;
#endif
}

// ---------------- kernel 1: weight prep + degree hist + edge rank ----------------
__global__ void prep_hist(const float* __restrict__ Wq, const float* __restrict__ Wk,
                          const float* __restrict__ Wv, const float* __restrict__ Wskip,
                          const float* __restrict__ bq, const float* __restrict__ bk,
                          const float* __restrict__ bv, const float* __restrict__ bskip,
                          const float* __restrict__ W1, const float* __restrict__ W2,
                          const int* __restrict__ dst, int* __restrict__ deg,
                          int* __restrict__ rank, int E,
                          ushort* __restrict__ Wcat_t, float* __restrict__ bcat,
                          ushort* __restrict__ W1t, ushort* __restrict__ W2t) {
  int b = blockIdx.x;
  if (b >= 256) {
    int t = (b - 256) * 256 + threadIdx.x;
    if (t < E) rank[t] = atomicAdd(&deg[dst[t]], 1);
    return;
  }
  int t = b * 256 + threadIdx.x;  // 0..65535
  {
    int w = t >> 14, c = (t >> 7) & 127, kk = t & 127;
    const float* W = (w == 0) ? Wq : (w == 1) ? Wk : (w == 2) ? Wv : Wskip;
    Wcat_t[t] = f2bf(W[kk * D + c]);
  }
  {
    int f = t >> 7, kk = t & 127;
    W1t[t] = f2bf(W1[kk * FF + f]);
  }
  {
    int c = t >> 9, f = t & 511;
    W2t[t] = f2bf(W2[f * D + c]);
  }
  if (t < 4 * D) {
    int w = t >> 7;
    const float* bb = (w == 0) ? bq : (w == 1) ? bk : (w == 2) ? bv : bskip;
    bcat[t] = bb[t & 127];
  }
}

// ---------------- kernel 2: exclusive scan of deg -> off[0..n] ----------------
__global__ __launch_bounds__(1024) void scan_kernel(const int* __restrict__ deg,
                                                    int* __restrict__ off, int n) {
  __shared__ int part[1024];
  int t = threadIdx.x;
  int chunk = (n + 1023) / 1024;
  int lo = t * chunk, hi = min(lo + chunk, n);
  int s = 0;
  for (int i = lo; i < hi; ++i) s += deg[i];
  part[t] = s;
  __syncthreads();
  for (int dd = 1; dd < 1024; dd <<= 1) {
    int v = (t >= dd) ? part[t - dd] : 0;
    __syncthreads();
    part[t] += v;
    __syncthreads();
  }
  int excl = (t == 0) ? 0 : part[t - 1];
  for (int i = lo; i < hi; ++i) {
    off[i] = excl;
    excl += deg[i];
  }
  if (t == 1023) off[n] = part[1023];
}

// ---------------- kernel 3: fused q/kv/xr GEMM (blocks < gm) + CSR permute ----------
__global__ __launch_bounds__(256) void gemm_scatter(
    const float* __restrict__ x, const ushort* __restrict__ Wcat_t,
    const float* __restrict__ bcat, ushort* __restrict__ qb, unsigned* __restrict__ kvf8,
    float* __restrict__ xr, int n, int gm,
    const int* __restrict__ dst, const int* __restrict__ src, const int* __restrict__ rank,
    const int* __restrict__ off, const float* __restrict__ attr, int* __restrict__ srcs,
    unsigned* __restrict__ attrh, int E) {
  if ((int)blockIdx.x >= gm) {
    int t = ((int)blockIdx.x - gm) * 256 + threadIdx.x;
    if (t < E) {
      int pos = off[dst[t]] + rank[t];
      srcs[pos] = src[t];
      const float2* ap = reinterpret_cast<const float2*>(attr + (size_t)t * ED);
#pragma unroll
      for (int j = 0; j < 5; ++j) {
        float2 av = ap[j];
        h2 hh = __builtin_amdgcn_cvt_pkrtz(av.x, av.y);
        attrh[(size_t)pos * 5 + j] = __builtin_bit_cast(unsigned, hh);
      }
    }
    return;
  }
  __shared__ ushort xa[32 * XPAD];  // 8704 B
  int r0 = blockIdx.x * 32;
  {
    int row = threadIdx.x >> 3;
    int seg = threadIdx.x & 7;
    int grow = min(r0 + row, n - 1);
    const float4* p = reinterpret_cast<const float4*>(x + (size_t)grow * D + seg * 16);
    float4 f0 = p[0], f1 = p[1], f2 = p[2], f3 = p[3];
    bf16x8 u0, u1;
    u0[0] = (short)f2bf(f0.x); u0[1] = (short)f2bf(f0.y);
    u0[2] = (short)f2bf(f0.z); u0[3] = (short)f2bf(f0.w);
    u0[4] = (short)f2bf(f1.x); u0[5] = (short)f2bf(f1.y);
    u0[6] = (short)f2bf(f1.z); u0[7] = (short)f2bf(f1.w);
    u1[0] = (short)f2bf(f2.x); u1[1] = (short)f2bf(f2.y);
    u1[2] = (short)f2bf(f2.z); u1[3] = (short)f2bf(f2.w);
    u1[4] = (short)f2bf(f3.x); u1[5] = (short)f2bf(f3.y);
    u1[6] = (short)f2bf(f3.z); u1[7] = (short)f2bf(f3.w);
    ushort* dl = xa + row * XPAD + seg * 16;
    *reinterpret_cast<bf16x8*>(dl) = u0;
    *reinterpret_cast<bf16x8*>(dl + 8) = u1;
  }
  __syncthreads();
  int wv = threadIdx.x >> 6;
  int l = threadIdx.x & 63;
  int lr = l & 15, lg = l >> 4;
  const ushort* Wt = Wcat_t + wv * D * D;
  f32x4 acc[2][8];
#pragma unroll
  for (int m = 0; m < 2; ++m)
#pragma unroll
    for (int nn = 0; nn < 8; ++nn) acc[m][nn] = (f32x4)0.f;
#pragma unroll
  for (int kb2 = 0; kb2 < 4; ++kb2) {
    int k0 = kb2 * 32 + lg * 8;
    bf16x8 a[2];
#pragma unroll
    for (int m = 0; m < 2; ++m)
      a[m] = *reinterpret_cast<const bf16x8*>(xa + (m * 16 + lr) * XPAD + k0);
    bf16x8 b[8];
#pragma unroll
    for (int nn = 0; nn < 8; ++nn)
      b[nn] = *reinterpret_cast<const bf16x8*>(Wt + (nn * 16 + lr) * D + k0);
#pragma unroll
    for (int m = 0; m < 2; ++m)
#pragma unroll
      for (int nn = 0; nn < 8; ++nn)
        acc[m][nn] = __builtin_amdgcn_mfma_f32_16x16x32_bf16(a[m], b[nn], acc[m][nn], 0, 0, 0);
  }
#pragma unroll
  for (int m = 0; m < 2; ++m)
#pragma unroll
    for (int nn = 0; nn < 8; ++nn) {
      int col = nn * 16 + lr;
      float bb = bcat[wv * D + col];
#pragma unroll
      for (int j = 0; j < 4; ++j) {
        int row = r0 + m * 16 + lg * 4 + j;
        float val = acc[m][nn][j] + bb;
        if (wv == 1 || wv == 2) {
          float partner = __shfl_xor(val, 1, 64);
          if (((lr & 1) == 0) && row < n) {
            ushort us = pack_fp8_pair(val, partner);
            size_t idx = ((size_t)row * 64 + nn * 8 + (lr >> 1)) * 2 + (wv - 1);
            reinterpret_cast<ushort*>(kvf8)[idx] = us;
          }
        } else if (row < n) {
          if (wv == 0) qb[(size_t)row * D + col] = f2bf(val);
          else xr[(size_t)row * D + col] = val;
        }
      }
    }
}

// ---------------- kernel 4: node-centric attention, 2 edges/PROC, 4 feats/lane --------
__global__ __launch_bounds__(256) void node_attn(
    const int* __restrict__ srcs, const int* __restrict__ off,
    const unsigned* __restrict__ attrh, const float* __restrict__ We,
    const ushort* __restrict__ qb, const unsigned* __restrict__ kvf8,
    const float* __restrict__ xr, const float* __restrict__ x,
    const float* __restrict__ Wbeta, float* __restrict__ h,
    float* __restrict__ sums, int n) {
  __shared__ uint4 attrS4[4][64];
  __shared__ unsigned attrS1[4][64];
  __shared__ float rs_h[4 * D], rs_h2[4 * D];
  int wid = threadIdx.x >> 6;
  int l = threadIdx.x & 63;
  int l5 = l & 31;       // lane within half
  int hb = l >> 5;       // 0: even edges, 1: odd edges
  int d0 = 4 * l5;       // this lane's 4 feature dims
  // We pairs for 4 dims: w4[j][t] = (We[2t][d0+j], We[2t+1][d0+j])
  h2 w4[4][5];
#pragma unroll
  for (int j = 0; j < 4; ++j)
#pragma unroll
    for (int t = 0; t < 5; ++t)
      w4[j][t] = __builtin_amdgcn_cvt_pkrtz(We[(2 * t) * D + d0 + j],
                                            We[(2 * t + 1) * D + d0 + j]);
  float4 wb0 = *reinterpret_cast<const float4*>(Wbeta + d0);
  float4 wb1 = *reinterpret_cast<const float4*>(Wbeta + D + d0);
  float4 wb2 = *reinterpret_cast<const float4*>(Wbeta + 2 * D + d0);
  float sh_[4] = {0.f, 0.f, 0.f, 0.f}, sh2_[4] = {0.f, 0.f, 0.f, 0.f};
  for (int node = blockIdx.x * 4 + wid; node < n; node += gridDim.x * 4) {
    ushort4 qu = *reinterpret_cast<const ushort4*>(qb + (size_t)node * D + d0);
    float q0 = bf2f(qu.x) * 0.25f, q1 = bf2f(qu.y) * 0.25f;
    float q2 = bf2f(qu.z) * 0.25f, q3 = bf2f(qu.w) * 0.25f;
    int o0 = off[node], dg = off[node + 1] - o0;
    float m = -1e30f, den = 0.f;
    float a0_ = 0.f, a1_ = 0.f, a2_ = 0.f, a3_ = 0.f;
    for (int chunk = 0; chunk < dg; chunk += 64) {
      int cnt = min(64, dg - chunk);
      // coalesced clamped staging by full wave (lane l stages edge l)
      long pos = (long)o0 + chunk + l;
      long pend = (long)o0 + dg - 1;
      if (pos > pend) pos = pend;
      int s_l = srcs[pos];
      {
        const unsigned* ah = attrh + (size_t)pos * 5;
        attrS4[wid][l] = make_uint4(ah[0], ah[1], ah[2], ah[3]);
        attrS1[wid][l] = ah[4];
      }
      int nproc = (cnt + 1) >> 1;
      auto LD = [&](int idx) -> uint2 {
        int ss = __shfl(s_l, (2 * idx + hb) & 63, 64);
        return *reinterpret_cast<const uint2*>(kvf8 + (size_t)ss * 64 + 2 * l5);
      };
      auto PROC = [&](uint2 kv, int i) {
        int ei = (2 * i + hb) & 63;
        bool valid = (2 * i + hb) < cnt;
        uint4 av = attrS4[wid][ei];
        unsigned av1 = attrS1[wid][ei];
        h2 t0 = __builtin_bit_cast(h2, av.x);
        h2 t1 = __builtin_bit_cast(h2, av.y);
        h2 t2 = __builtin_bit_cast(h2, av.z);
        h2 t3 = __builtin_bit_cast(h2, av.w);
        h2 t4 = __builtin_bit_cast(h2, av1);
        float ec0 = __builtin_amdgcn_fdot2(t0, w4[0][0], 0.f, false);
        ec0 = __builtin_amdgcn_fdot2(t1, w4[0][1], ec0, false);
        ec0 = __builtin_amdgcn_fdot2(t2, w4[0][2], ec0, false);
        ec0 = __builtin_amdgcn_fdot2(t3, w4[0][3], ec0, false);
        ec0 = __builtin_amdgcn_fdot2(t4, w4[0][4], ec0, false);
        float ec1 = __builtin_amdgcn_fdot2(t0, w4[1][0], 0.f, false);
        ec1 = __builtin_amdgcn_fdot2(t1, w4[1][1], ec1, false);
        ec1 = __builtin_amdgcn_fdot2(t2, w4[1][2], ec1, false);
        ec1 = __builtin_amdgcn_fdot2(t3, w4[1][3], ec1, false);
        ec1 = __builtin_amdgcn_fdot2(t4, w4[1][4], ec1, false);
        float ec2 = __builtin_amdgcn_fdot2(t0, w4[2][0], 0.f, false);
        ec2 = __builtin_amdgcn_fdot2(t1, w4[2][1], ec2, false);
        ec2 = __builtin_amdgcn_fdot2(t2, w4[2][2], ec2, false);
        ec2 = __builtin_amdgcn_fdot2(t3, w4[2][3], ec2, false);
        ec2 = __builtin_amdgcn_fdot2(t4, w4[2][4], ec2, false);
        float ec3 = __builtin_amdgcn_fdot2(t0, w4[3][0], 0.f, false);
        ec3 = __builtin_amdgcn_fdot2(t1, w4[3][1], ec3, false);
        ec3 = __builtin_amdgcn_fdot2(t2, w4[3][2], ec3, false);
        ec3 = __builtin_amdgcn_fdot2(t3, w4[3][3], ec3, false);
        ec3 = __builtin_amdgcn_fdot2(t4, w4[3][4], ec3, false);
        f32x2 k01 = unpack_fp8_pair<false>(kv.x);
        f32x2 k23 = unpack_fp8_pair<false>(kv.y);
        f32x2 v01 = unpack_fp8_pair<true>(kv.x);
        f32x2 v23 = unpack_fp8_pair<true>(kv.y);
        float p = q0 * (k01[0] + ec0);
        p = fmaf(q1, k01[1] + ec1, p);
        p = fmaf(q2, k23[0] + ec2, p);
        p = fmaf(q3, k23[1] + ec3, p);
        p = dpp_add_xor1(p);
        p = dpp_add_xor2(p);  // head = 4 lanes: reduce complete, all DPP
        if (__any(p > m + 8.f)) {
          float mn = fmaxf(m, p);
          float sc = __expf(m - mn);
          den *= sc; a0_ *= sc; a1_ *= sc; a2_ *= sc; a3_ *= sc;
          m = mn;
        }
        float ex = valid ? __expf(p - m) : 0.f;
        den += ex;
        a0_ = fmaf(ex, v01[0] + ec0, a0_);
        a1_ = fmaf(ex, v01[1] + ec1, a1_);
        a2_ = fmaf(ex, v23[0] + ec2, a2_);
        a3_ = fmaf(ex, v23[1] + ec3, a3_);
      };
      uint2 p0 = LD(0), p1 = LD(1), p2 = LD(2), p3 = LD(3),
            p4 = LD(4), p5 = LD(5), p6 = LD(6), p7 = LD(7);
      for (int i = 0; i < nproc; i += 8) {
        uint2 c0 = p0, c1 = p1, c2 = p2, c3 = p3, c4 = p4, c5 = p5, c6 = p6, c7 = p7;
        p0 = LD(i + 8);  p1 = LD(i + 9);  p2 = LD(i + 10); p3 = LD(i + 11);
        p4 = LD(i + 12); p5 = LD(i + 13); p6 = LD(i + 14); p7 = LD(i + 15);
        PROC(c0, i);
        if (i + 1 < nproc) PROC(c1, i + 1);
        if (i + 2 < nproc) PROC(c2, i + 2);
        if (i + 3 < nproc) PROC(c3, i + 3);
        if (i + 4 < nproc) PROC(c4, i + 4);
        if (i + 5 < nproc) PROC(c5, i + 5);
        if (i + 6 < nproc) PROC(c6, i + 6);
        if (i + 7 < nproc) PROC(c7, i + 7);
      }
    }
    // flash-style merge of the two halves (lane l <-> l^32)
    float mB = __shfl_xor(m, 32, 64);
    float denB = __shfl_xor(den, 32, 64);
    float b0 = __shfl_xor(a0_, 32, 64);
    float b1 = __shfl_xor(a1_, 32, 64);
    float b2 = __shfl_xor(a2_, 32, 64);
    float b3 = __shfl_xor(a3_, 32, 64);
    float mT = fmaxf(m, mB);
    float sA = __expf(m - mT), sB = __expf(mB - mT);
    float denT = den * sA + denB * sB;
    float inv = 1.f / (denT + 1e-16f);
    float oo0 = (a0_ * sA + b0 * sB) * inv;
    float oo1 = (a1_ * sA + b1 * sB) * inv;
    float oo2 = (a2_ * sA + b2 * sB) * inv;
    float oo3 = (a3_ * sA + b3 * sB) * inv;
    float4 xr4 = *reinterpret_cast<const float4*>(xr + (size_t)node * D + d0);
    float4 x4 = *reinterpret_cast<const float4*>(x + (size_t)node * D + d0);
    float pb = oo0 * wb0.x + xr4.x * wb1.x + (oo0 - xr4.x) * wb2.x
             + oo1 * wb0.y + xr4.y * wb1.y + (oo1 - xr4.y) * wb2.y
             + oo2 * wb0.z + xr4.z * wb1.z + (oo2 - xr4.z) * wb2.z
             + oo3 * wb0.w + xr4.w * wb1.w + (oo3 - xr4.w) * wb2.w;
#pragma unroll
    for (int msk = 1; msk < 32; msk <<= 1) pb += __shfl_xor(pb, msk, 32);
    float beta = 1.f / (1.f + __expf(-pb));
    float h0 = x4.x + beta * xr4.x + (1.f - beta) * oo0;
    float h1 = x4.y + beta * xr4.y + (1.f - beta) * oo1;
    float h2_ = x4.z + beta * xr4.z + (1.f - beta) * oo2;
    float h3 = x4.w + beta * xr4.w + (1.f - beta) * oo3;
    if (hb == 0) {
      *reinterpret_cast<float4*>(h + (size_t)node * D + d0) = make_float4(h0, h1, h2_, h3);
      sh_[0] += h0; sh2_[0] += h0 * h0;
      sh_[1] += h1; sh2_[1] += h1 * h1;
      sh_[2] += h2_; sh2_[2] += h2_ * h2_;
      sh_[3] += h3; sh2_[3] += h3 * h3;
    }
  }
  if (hb == 0) {
#pragma unroll
    for (int j = 0; j < 4; ++j) {
      rs_h[wid * D + d0 + j] = sh_[j];
      rs_h2[wid * D + d0 + j] = sh2_[j];
    }
  }
  __syncthreads();
  if (threadIdx.x < D) {
    int d = threadIdx.x;
    float sh = rs_h[d] + rs_h[D + d] + rs_h[2 * D + d] + rs_h[3 * D + d];
    float sh2 = rs_h2[d] + rs_h2[D + d] + rs_h2[2 * D + d] + rs_h2[3 * D + d];
    atomicAdd(&sums[d], sh);
    atomicAdd(&sums[D + d], sh2);
  }
}

// ---------------- kernel 5: fused GraphNorm-stats + FFN, LDS-staged ----------------
__global__ __launch_bounds__(256) void ffn_fused(
    const float* __restrict__ h, const float* __restrict__ sums,
    const float* __restrict__ gn_w, const float* __restrict__ gn_b,
    const float* __restrict__ gn_ms,
    const ushort* __restrict__ W1t, const float* __restrict__ b1,
    const ushort* __restrict__ W2t, const float* __restrict__ b2,
    float* __restrict__ out, float inv_n, int n) {
  __shared__ ushort xa[32 * XPAD];
  __shared__ ushort tt[32 * TPAD];
  __shared__ float scsh[2 * D];
  if (threadIdx.x < D) {
    int d = threadIdx.x;
    float mean = sums[d] * inv_n;
    float ex2 = sums[D + d] * inv_n;
    float ms = gn_ms[d];
    float var = ex2 - 2.f * ms * mean * mean + ms * ms * mean * mean;
    float inv = 1.f / sqrtf(var + 1e-5f);
    float scale = gn_w[d] * inv;
    scsh[d] = scale;
    scsh[D + d] = gn_b[d] - ms * mean * scale;
  }
  __syncthreads();
  int r0 = blockIdx.x * 32;
  {
    int row = threadIdx.x >> 3;
    int seg = threadIdx.x & 7;
    int grow = min(r0 + row, n - 1);
    const float4* p = reinterpret_cast<const float4*>(h + (size_t)grow * D + seg * 16);
    float4 f0 = p[0], f1 = p[1], f2 = p[2], f3 = p[3];
    const float4* sc = reinterpret_cast<const float4*>(scsh + seg * 16);
    const float4* sh = reinterpret_cast<const float4*>(scsh + D + seg * 16);
    float4 s0 = sc[0], s1 = sc[1], s2 = sc[2], s3 = sc[3];
    float4 t0 = sh[0], t1 = sh[1], t2 = sh[2], t3 = sh[3];
    bf16x8 u0, u1;
    u0[0] = (short)f2bf(f0.x * s0.x + t0.x); u0[1] = (short)f2bf(f0.y * s0.y + t0.y);
    u0[2] = (short)f2bf(f0.z * s0.z + t0.z); u0[3] = (short)f2bf(f0.w * s0.w + t0.w);
    u0[4] = (short)f2bf(f1.x * s1.x + t1.x); u0[5] = (short)f2bf(f1.y * s1.y + t1.y);
    u0[6] = (short)f2bf(f1.z * s1.z + t1.z); u0[7] = (short)f2bf(f1.w * s1.w + t1.w);
    u1[0] = (short)f2bf(f2.x * s2.x + t2.x); u1[1] = (short)f2bf(f2.y * s2.y + t2.y);
    u1[2] = (short)f2bf(f2.z * s2.z + t2.z); u1[3] = (short)f2bf(f2.w * s2.w + t2.w);
    u1[4] = (short)f2bf(f3.x * s3.x + t3.x); u1[5] = (short)f2bf(f3.y * s3.y + t3.y);
    u1[6] = (short)f2bf(f3.z * s3.z + t3.z); u1[7] = (short)f2bf(f3.w * s3.w + t3.w);
    ushort* dl = xa + row * XPAD + seg * 16;
    *reinterpret_cast<bf16x8*>(dl) = u0;
    *reinterpret_cast<bf16x8*>(dl + 8) = u1;
  }
  __syncthreads();
  int wv = threadIdx.x >> 6;
  int l = threadIdx.x & 63;
  int lr = l & 15, lg = l >> 4;
  int c0 = wv * 128;
  {
    f32x4 acc[2][8];
#pragma unroll
    for (int m = 0; m < 2; ++m)
#pragma unroll
      for (int nn = 0; nn < 8; ++nn) acc[m][nn] = (f32x4)0.f;
#pragma unroll
    for (int kb = 0; kb < 4; ++kb) {
      int k0 = kb * 32 + lg * 8;
      bf16x8 a[2];
#pragma unroll
      for (int m = 0; m < 2; ++m)
        a[m] = *reinterpret_cast<const bf16x8*>(xa + (m * 16 + lr) * XPAD + k0);
      bf16x8 b[8];
#pragma unroll
      for (int nn = 0; nn < 8; ++nn)
        b[nn] = *reinterpret_cast<const bf16x8*>(W1t + (c0 + nn * 16 + lr) * D + k0);
#pragma unroll
      for (int m = 0; m < 2; ++m)
#pragma unroll
        for (int nn = 0; nn < 8; ++nn)
          acc[m][nn] = __builtin_amdgcn_mfma_f32_16x16x32_bf16(a[m], b[nn], acc[m][nn], 0, 0, 0);
    }
    const float inv_sqrt2 = 0.70710678118654752440f;
#pragma unroll
    for (int m = 0; m < 2; ++m)
#pragma unroll
      for (int nn = 0; nn < 8; ++nn) {
        int col = c0 + nn * 16 + lr;
        float bb = b1[col];
#pragma unroll
        for (int j = 0; j < 4; ++j) {
          int rowl = m * 16 + lg * 4 + j;
          float val = acc[m][nn][j] + bb;
          val = 0.5f * val * (1.f + erff(val * inv_sqrt2));
          tt[rowl * TPAD + col] = f2bf(val);
        }
      }
  }
  __syncthreads();
  {
    f32x4 acc[2][2];
#pragma unroll
    for (int m = 0; m < 2; ++m)
#pragma unroll
      for (int nn = 0; nn < 2; ++nn) acc[m][nn] = (f32x4)0.f;
#pragma unroll 4
    for (int kb = 0; kb < 16; ++kb) {
      int k0 = kb * 32 + lg * 8;
      bf16x8 a[2];
#pragma unroll
      for (int m = 0; m < 2; ++m)
        a[m] = *reinterpret_cast<const bf16x8*>(tt + (m * 16 + lr) * TPAD + k0);
      bf16x8 b[2];
#pragma unroll
      for (int nn = 0; nn < 2; ++nn)
        b[nn] = *reinterpret_cast<const bf16x8*>(W2t + (wv * 32 + nn * 16 + lr) * FF + k0);
#pragma unroll
      for (int m = 0; m < 2; ++m)
#pragma unroll
        for (int nn = 0; nn < 2; ++nn)
          acc[m][nn] = __builtin_amdgcn_mfma_f32_16x16x32_bf16(a[m], b[nn], acc[m][nn], 0, 0, 0);
    }
#pragma unroll
    for (int m = 0; m < 2; ++m)
#pragma unroll
      for (int nn = 0; nn < 2; ++nn) {
        int col = wv * 32 + nn * 16 + lr;
        float bb = b2[col];
#pragma unroll
        for (int j = 0; j < 4; ++j) {
          int rowl = m * 16 + lg * 4 + j;
          int row = r0 + rowl;
          if (row < n) {
            float hn = bf2f(xa[rowl * XPAD + col]);
            out[(size_t)row * D + col] = hn + acc[m][nn][j] + bb;
          }
        }
      }
  }
}

extern "C" void kernel_launch(void* const* d_in, const int* in_sizes, int n_in,
                              void* d_out, int out_size, void* d_ws, size_t ws_size,
                              hipStream_t stream) {
  const float* x     = (const float*)d_in[0];
  const int*   ei    = (const int*)d_in[1];
  const float* attr  = (const float*)d_in[2];
  const float* Wq    = (const float*)d_in[3];
  const float* bq    = (const float*)d_in[4];
  const float* Wk    = (const float*)d_in[5];
  const float* bk    = (const float*)d_in[6];
  const float* Wv    = (const float*)d_in[7];
  const float* bv    = (const float*)d_in[8];
  const float* We    = (const float*)d_in[9];
  const float* Wskip = (const float*)d_in[10];
  const float* bskip = (const float*)d_in[11];
  const float* Wbeta = (const float*)d_in[12];
  const float* gn_w  = (const float*)d_in[13];
  const float* gn_b  = (const float*)d_in[14];
  const float* gn_ms = (const float*)d_in[15];
  const float* W1    = (const float*)d_in[16];
  const float* b1    = (const float*)d_in[17];
  const float* W2    = (const float*)d_in[18];
  const float* b2    = (const float*)d_in[19];

  const int n = in_sizes[0] / D;
  const int E = in_sizes[1] / 2;
  const int* src = ei;
  const int* dst = ei + E;
  const size_t ND = (size_t)n * D;

  // ---- workspace layout ----
  ushort* qb = (ushort*)d_ws;                  // ND bf16
  unsigned* kvf8 = (unsigned*)(qb + ND);       // n*64 uints (fp8 k/v interleaved)
  float* xr = (float*)(kvf8 + (size_t)n * 64); // ND f32
  int* deg = (int*)(xr + ND);                  // n    (zeroed)
  float* sums = (float*)(deg + n);             // 2D   (zeroed)
  int* off = (int*)(sums + 2 * D);             // n+1
  int* srcs = off + n + 1;                     // E (dst-sorted src ids)
  int* rank = srcs + E;                        // E
  unsigned* attrh = (unsigned*)(rank + E);     // E*5 (dst-sorted half attrs)
  ushort* Wcat_t = (ushort*)(attrh + (size_t)E * 5);  // 4*D*D
  ushort* W1t = Wcat_t + 4 * D * D;            // D*FF
  ushort* W2t = W1t + D * FF;                  // FF*D
  float* bcat = (float*)(W2t + FF * D);        // 4D

  (void)hipMemsetAsync(deg, 0, ((size_t)n + 2 * D) * sizeof(int), stream);

  int ghist = (E + 255) / 256;
  prep_hist<<<256 + ghist, 256, 0, stream>>>(Wq, Wk, Wv, Wskip, bq, bk, bv, bskip, W1, W2,
                                             dst, deg, rank, E, Wcat_t, bcat, W1t, W2t);
  scan_kernel<<<1, 1024, 0, stream>>>(deg, off, n);

  int gm = (n + 31) / 32;
  gemm_scatter<<<gm + ghist, 256, 0, stream>>>(x, Wcat_t, bcat, qb, kvf8, xr, n, gm, dst,
                                               src, rank, off, attr, srcs, attrh, E);

  node_attn<<<2048, 256, 0, stream>>>(srcs, off, attrh, We, qb, kvf8, xr, x, Wbeta,
                                      (float*)d_out, sums, n);

  ffn_fused<<<(n + 31) / 32, 256, 0, stream>>>((const float*)d_out, sums, gn_w, gn_b, gn_ms,
                                               W1t, b1, W2t, b2, (float*)d_out,
                                               1.f / (float)n, n);
}

// Round 14
// 375.985 us; speedup vs baseline: 1.0367x; 1.0367x over previous
//
#include <hip/hip_runtime.h>
#include <hip/hip_fp16.h>
#include <math.h>

#define D 128
#define ED 10
#define FF 512
#define TPAD 520   // bf16 per LDS row in ffn t-tile (512 + 8 pad)
#define XPAD 136   // bf16 per LDS row for 128-wide tiles (128 + 8 pad)

typedef __attribute__((ext_vector_type(4))) float f32x4;
typedef __attribute__((ext_vector_type(8))) short bf16x8;
using h2 = decltype(__builtin_amdgcn_cvt_pkrtz(0.f, 0.f));  // __fp16 ext_vector(2)
typedef __attribute__((ext_vector_type(2))) float f32x2;

__device__ __forceinline__ ushort f2bf(float f) {
  unsigned u = __float_as_uint(f);
  unsigned r = u + 0x7fffu + ((u >> 16) & 1u);
  return (ushort)(r >> 16);
}
__device__ __forceinline__ float bf2f(ushort u) {
  return __uint_as_float(((unsigned)u) << 16);
}

// in-quad butterfly add via DPP (VALU pipe): 0xB1 = xor1, 0x4E = xor2
__device__ __forceinline__ float dpp_add_xor1(float x) {
  int y = __builtin_amdgcn_update_dpp(0, __builtin_bit_cast(int, x), 0xB1, 0xF, 0xF, true);
  return x + __builtin_bit_cast(float, y);
}
__device__ __forceinline__ float dpp_add_xor2(float x) {
  int y = __builtin_amdgcn_update_dpp(0, __builtin_bit_cast(int, x), 0x4E, 0xF, 0xF, true);
  return x + __builtin_bit_cast(float, y);
}

// ---- fp8 e4m3 pack/unpack ----
#if __has_builtin(__builtin_amdgcn_cvt_pk_f32_fp8) && __has_builtin(__builtin_amdgcn_cvt_pk_fp8_f32)
#define FP8_HW 1
#else
#define FP8_HW 0
#endif

__device__ __forceinline__ unsigned sw_f2fp8(float f) {
  unsigned u = __float_as_uint(f);
  unsigned s = (u >> 24) & 0x80;
  int e = (int)((u >> 23) & 0xff) - 127;
  unsigned mant = u & 0x7fffff;
  if (e < -9) return s;
  if (e > 8) return s | 0x7e;
  if (e >= -6) {
    unsigned m = mant + 0x7ffff + ((mant >> 20) & 1);
    if (m >= 0x800000) { m = 0; ++e; if (e > 8) return s | 0x7e; }
    return s | ((unsigned)(e + 7) << 3) | (m >> 20);
  }
  unsigned full = 0x800000 | mant;
  int shift = 20 + (-6 - e);
  unsigned m = (full + (1u << (shift - 1)) + ((full >> shift) & 1)) >> shift;
  if (m >= 8) return s | 0x08;
  return s | m;
}
__device__ __forceinline__ float sw_fp82f(unsigned b) {
  unsigned s = (b & 0x80) << 24;
  unsigned e = (b >> 3) & 0xf;
  unsigned m = b & 7;
  if (e == 0) {
    if (m == 0) return __uint_as_float(s);
    float v = (float)(int)m * 0.001953125f;
    return (b & 0x80) ? -v : v;
  }
  return __uint_as_float(s | ((e + 120) << 23) | (m << 20));
}

__device__ __forceinline__ ushort pack_fp8_pair(float a, float b) {
#if FP8_HW
  int r = __builtin_amdgcn_cvt_pk_fp8_f32(a, b, 0, false);
  return (ushort)(r & 0xffff);
#else
  return (ushort)(sw_f2fp8(a) | (sw_f2fp8(b) << 8));
#endif
}
template <bool HI>
__device__ __forceinline__ f32x2 unpack_fp8_pair(unsigned w) {
#if FP8_HW
  auto r = __builtin_amdgcn_cvt_pk_f32_fp8((int)w, HI);
  f32x2 o; o[0] = r[0]; o[1] = r[1];
  return o;
#else
  unsigned v = HI ? (w >> 16) : w;
  f32x2 o; o[0] = sw_fp82f(v & 0xff); o[1] = sw_fp82f((v >> 8) & 0xff);
  return o;
#endif
}

// ---------------- kernel 1: weight prep + degree hist + edge rank ----------------
__global__ void prep_hist(const float* __restrict__ Wq, const float* __restrict__ Wk,
                          const float* __restrict__ Wv, const float* __restrict__ Wskip,
                          const float* __restrict__ bq, const float* __restrict__ bk,
                          const float* __restrict__ bv, const float* __restrict__ bskip,
                          const float* __restrict__ W1, const float* __restrict__ W2,
                          const int* __restrict__ dst, int* __restrict__ deg,
                          int* __restrict__ rank, int E,
                          ushort* __restrict__ Wcat_t, float* __restrict__ bcat,
                          ushort* __restrict__ W1t, ushort* __restrict__ W2t) {
  int b = blockIdx.x;
  if (b >= 256) {
    int t = (b - 256) * 256 + threadIdx.x;
    if (t < E) rank[t] = atomicAdd(&deg[dst[t]], 1);
    return;
  }
  int t = b * 256 + threadIdx.x;  // 0..65535
  {
    int w = t >> 14, c = (t >> 7) & 127, kk = t & 127;
    const float* W = (w == 0) ? Wq : (w == 1) ? Wk : (w == 2) ? Wv : Wskip;
    Wcat_t[t] = f2bf(W[kk * D + c]);
  }
  {
    int f = t >> 7, kk = t & 127;
    W1t[t] = f2bf(W1[kk * FF + f]);
  }
  {
    int c = t >> 9, f = t & 511;
    W2t[t] = f2bf(W2[f * D + c]);
  }
  if (t < 4 * D) {
    int w = t >> 7;
    const float* bb = (w == 0) ? bq : (w == 1) ? bk : (w == 2) ? bv : bskip;
    bcat[t] = bb[t & 127];
  }
}

// ---------------- kernel 2: exclusive scan of deg -> off[0..n] ----------------
__global__ __launch_bounds__(1024) void scan_kernel(const int* __restrict__ deg,
                                                    int* __restrict__ off, int n) {
  __shared__ int part[1024];
  int t = threadIdx.x;
  int chunk = (n + 1023) / 1024;
  int lo = t * chunk, hi = min(lo + chunk, n);
  int s = 0;
  for (int i = lo; i < hi; ++i) s += deg[i];
  part[t] = s;
  __syncthreads();
  for (int dd = 1; dd < 1024; dd <<= 1) {
    int v = (t >= dd) ? part[t - dd] : 0;
    __syncthreads();
    part[t] += v;
    __syncthreads();
  }
  int excl = (t == 0) ? 0 : part[t - 1];
  for (int i = lo; i < hi; ++i) {
    off[i] = excl;
    excl += deg[i];
  }
  if (t == 1023) off[n] = part[1023];
}

// ---------------- kernel 3: fused q/kv/xr GEMM (blocks < gm) + CSR permute ----------
// scatter writes 32B-aligned edge records: [src, attr0..4, 0, 0]
__global__ __launch_bounds__(256) void gemm_scatter(
    const float* __restrict__ x, const ushort* __restrict__ Wcat_t,
    const float* __restrict__ bcat, ushort* __restrict__ qb, unsigned* __restrict__ kvf8,
    float* __restrict__ xr, int n, int gm,
    const int* __restrict__ dst, const int* __restrict__ src, const int* __restrict__ rank,
    const int* __restrict__ off, const float* __restrict__ attr,
    unsigned* __restrict__ rec, int E) {
  if ((int)blockIdx.x >= gm) {
    int t = ((int)blockIdx.x - gm) * 256 + threadIdx.x;
    if (t < E) {
      int pos = off[dst[t]] + rank[t];
      const float2* ap = reinterpret_cast<const float2*>(attr + (size_t)t * ED);
      float2 a0 = ap[0], a1 = ap[1], a2 = ap[2], a3 = ap[3], a4 = ap[4];
      unsigned u0 = __builtin_bit_cast(unsigned, __builtin_amdgcn_cvt_pkrtz(a0.x, a0.y));
      unsigned u1 = __builtin_bit_cast(unsigned, __builtin_amdgcn_cvt_pkrtz(a1.x, a1.y));
      unsigned u2 = __builtin_bit_cast(unsigned, __builtin_amdgcn_cvt_pkrtz(a2.x, a2.y));
      unsigned u3 = __builtin_bit_cast(unsigned, __builtin_amdgcn_cvt_pkrtz(a3.x, a3.y));
      unsigned u4 = __builtin_bit_cast(unsigned, __builtin_amdgcn_cvt_pkrtz(a4.x, a4.y));
      uint4* rp = reinterpret_cast<uint4*>(rec + (size_t)pos * 8);
      rp[0] = make_uint4((unsigned)src[t], u0, u1, u2);
      rp[1] = make_uint4(u3, u4, 0u, 0u);
    }
    return;
  }
  __shared__ ushort xa[32 * XPAD];  // 8704 B
  int r0 = blockIdx.x * 32;
  {
    int row = threadIdx.x >> 3;
    int seg = threadIdx.x & 7;
    int grow = min(r0 + row, n - 1);
    const float4* p = reinterpret_cast<const float4*>(x + (size_t)grow * D + seg * 16);
    float4 f0 = p[0], f1 = p[1], f2 = p[2], f3 = p[3];
    bf16x8 u0, u1;
    u0[0] = (short)f2bf(f0.x); u0[1] = (short)f2bf(f0.y);
    u0[2] = (short)f2bf(f0.z); u0[3] = (short)f2bf(f0.w);
    u0[4] = (short)f2bf(f1.x); u0[5] = (short)f2bf(f1.y);
    u0[6] = (short)f2bf(f1.z); u0[7] = (short)f2bf(f1.w);
    u1[0] = (short)f2bf(f2.x); u1[1] = (short)f2bf(f2.y);
    u1[2] = (short)f2bf(f2.z); u1[3] = (short)f2bf(f2.w);
    u1[4] = (short)f2bf(f3.x); u1[5] = (short)f2bf(f3.y);
    u1[6] = (short)f2bf(f3.z); u1[7] = (short)f2bf(f3.w);
    ushort* dl = xa + row * XPAD + seg * 16;
    *reinterpret_cast<bf16x8*>(dl) = u0;
    *reinterpret_cast<bf16x8*>(dl + 8) = u1;
  }
  __syncthreads();
  int wv = threadIdx.x >> 6;
  int l = threadIdx.x & 63;
  int lr = l & 15, lg = l >> 4;
  const ushort* Wt = Wcat_t + wv * D * D;
  f32x4 acc[2][8];
#pragma unroll
  for (int m = 0; m < 2; ++m)
#pragma unroll
    for (int nn = 0; nn < 8; ++nn) acc[m][nn] = (f32x4)0.f;
#pragma unroll
  for (int kb2 = 0; kb2 < 4; ++kb2) {
    int k0 = kb2 * 32 + lg * 8;
    bf16x8 a[2];
#pragma unroll
    for (int m = 0; m < 2; ++m)
      a[m] = *reinterpret_cast<const bf16x8*>(xa + (m * 16 + lr) * XPAD + k0);
    bf16x8 b[8];
#pragma unroll
    for (int nn = 0; nn < 8; ++nn)
      b[nn] = *reinterpret_cast<const bf16x8*>(Wt + (nn * 16 + lr) * D + k0);
#pragma unroll
    for (int m = 0; m < 2; ++m)
#pragma unroll
      for (int nn = 0; nn < 8; ++nn)
        acc[m][nn] = __builtin_amdgcn_mfma_f32_16x16x32_bf16(a[m], b[nn], acc[m][nn], 0, 0, 0);
  }
#pragma unroll
  for (int m = 0; m < 2; ++m)
#pragma unroll
    for (int nn = 0; nn < 8; ++nn) {
      int col = nn * 16 + lr;
      float bb = bcat[wv * D + col];
#pragma unroll
      for (int j = 0; j < 4; ++j) {
        int row = r0 + m * 16 + lg * 4 + j;
        float val = acc[m][nn][j] + bb;
        if (wv == 1 || wv == 2) {
          float partner = __shfl_xor(val, 1, 64);
          if (((lr & 1) == 0) && row < n) {
            ushort us = pack_fp8_pair(val, partner);
            size_t idx = ((size_t)row * 64 + nn * 8 + (lr >> 1)) * 2 + (wv - 1);
            reinterpret_cast<ushort*>(kvf8)[idx] = us;
          }
        } else if (row < n) {
          if (wv == 0) qb[(size_t)row * D + col] = f2bf(val);
          else xr[(size_t)row * D + col] = val;
        }
      }
    }
}

// ---------------- kernel 4: node-centric attention, 8-deep pipelined, fp8 kv ----------
// (round-12 structure: 2 dims/lane, head = 8 lanes; 32B record staging)
__global__ __launch_bounds__(256) void node_attn(
    const unsigned* __restrict__ rec, const int* __restrict__ off,
    const float* __restrict__ We, const ushort* __restrict__ qb,
    const unsigned* __restrict__ kvf8, const float* __restrict__ xr,
    const float* __restrict__ x, const float* __restrict__ Wbeta,
    float* __restrict__ h, float* __restrict__ sums, int n) {
  __shared__ uint4 attrS4[4][64];      // attrs dwords 0..3  (b128 read)
  __shared__ unsigned attrS1[4][64];   // attrs dword 4      (b32 read)
  __shared__ float rs_h[4 * D], rs_h2[4 * D];
  int wid = threadIdx.x >> 6;
  int l = threadIdx.x & 63;
  int d0 = 2 * l;
  h2 wA[5], wB[5];
#pragma unroll
  for (int t = 0; t < 5; ++t) {
    wA[t] = __builtin_amdgcn_cvt_pkrtz(We[(2 * t) * D + d0], We[(2 * t + 1) * D + d0]);
    wB[t] = __builtin_amdgcn_cvt_pkrtz(We[(2 * t) * D + d0 + 1], We[(2 * t + 1) * D + d0 + 1]);
  }
  float2 wb0 = *reinterpret_cast<const float2*>(Wbeta + d0);
  float2 wb1 = *reinterpret_cast<const float2*>(Wbeta + D + d0);
  float2 wb2 = *reinterpret_cast<const float2*>(Wbeta + 2 * D + d0);
  float s_h0 = 0.f, s_h20 = 0.f, s_h1 = 0.f, s_h21 = 0.f;
  for (int node = blockIdx.x * 4 + wid; node < n; node += gridDim.x * 4) {
    const ushort2 qu = *reinterpret_cast<const ushort2*>(qb + (size_t)node * D + d0);
    float q0 = bf2f(qu.x) * 0.25f, q1 = bf2f(qu.y) * 0.25f;
    int o0 = off[node], dg = off[node + 1] - o0;
    float m = -1e30f, den = 0.f, acc0 = 0.f, acc1 = 0.f;
    for (int chunk = 0; chunk < dg; chunk += 64) {
      int cnt = min(64, dg - chunk);
      // coalesced clamped staging: 32B-aligned records -> 2x dwordx4 loads
      long pos = (long)o0 + chunk + l;
      long pend = (long)o0 + dg - 1;
      if (pos > pend) pos = pend;
      const uint4* rp = reinterpret_cast<const uint4*>(rec + (size_t)pos * 8);
      uint4 rA = rp[0], rB = rp[1];
      int s_l = (int)rA.x;
      attrS4[wid][l] = make_uint4(rA.y, rA.z, rA.w, rB.x);
      attrS1[wid][l] = rB.y;
      auto LD = [&](int idx) -> unsigned {
        int ss = __shfl(s_l, idx & 63, 64);  // wrap-safe: all lanes valid
        return kvf8[(size_t)ss * 64 + l];
      };
      auto PROC = [&](unsigned kvw, int i) {
        uint4 av = attrS4[wid][i];
        unsigned av1 = attrS1[wid][i];
        h2 a0 = __builtin_bit_cast(h2, av.x);
        h2 a1 = __builtin_bit_cast(h2, av.y);
        h2 a2 = __builtin_bit_cast(h2, av.z);
        h2 a3 = __builtin_bit_cast(h2, av.w);
        h2 a4 = __builtin_bit_cast(h2, av1);
        float ec0 = __builtin_amdgcn_fdot2(a0, wA[0], 0.f, false);
        ec0 = __builtin_amdgcn_fdot2(a1, wA[1], ec0, false);
        ec0 = __builtin_amdgcn_fdot2(a2, wA[2], ec0, false);
        ec0 = __builtin_amdgcn_fdot2(a3, wA[3], ec0, false);
        ec0 = __builtin_amdgcn_fdot2(a4, wA[4], ec0, false);
        float ec1 = __builtin_amdgcn_fdot2(a0, wB[0], 0.f, false);
        ec1 = __builtin_amdgcn_fdot2(a1, wB[1], ec1, false);
        ec1 = __builtin_amdgcn_fdot2(a2, wB[2], ec1, false);
        ec1 = __builtin_amdgcn_fdot2(a3, wB[3], ec1, false);
        ec1 = __builtin_amdgcn_fdot2(a4, wB[4], ec1, false);
        f32x2 kf = unpack_fp8_pair<false>(kvw);
        f32x2 vf = unpack_fp8_pair<true>(kvw);
        float kk0 = kf[0] + ec0, kk1 = kf[1] + ec1;
        float vv0 = vf[0] + ec0, vv1 = vf[1] + ec1;
        float p = fmaf(q0, kk0, q1 * kk1);
        p = dpp_add_xor1(p);       // xor1 (VALU/DPP)
        p = dpp_add_xor2(p);       // xor2 (VALU/DPP)
        p += __shfl_xor(p, 4, 8);  // xor4 (DS)
        if (__any(p > m + 8.f)) {
          float mn = fmaxf(m, p);
          float sc = __expf(m - mn);
          den *= sc; acc0 *= sc; acc1 *= sc;
          m = mn;
        }
        float ex = __expf(p - m);
        den += ex;
        acc0 = fmaf(ex, vv0, acc0);
        acc1 = fmaf(ex, vv1, acc1);
      };
      unsigned p0 = LD(0), p1 = LD(1), p2 = LD(2), p3 = LD(3),
               p4 = LD(4), p5 = LD(5), p6 = LD(6), p7 = LD(7);
      for (int i = 0; i < cnt; i += 8) {
        unsigned c0 = p0, c1 = p1, c2 = p2, c3 = p3, c4 = p4, c5 = p5, c6 = p6, c7 = p7;
        p0 = LD(i + 8);  p1 = LD(i + 9);  p2 = LD(i + 10); p3 = LD(i + 11);
        p4 = LD(i + 12); p5 = LD(i + 13); p6 = LD(i + 14); p7 = LD(i + 15);
        PROC(c0, i);
        if (i + 1 < cnt) PROC(c1, i + 1);
        if (i + 2 < cnt) PROC(c2, i + 2);
        if (i + 3 < cnt) PROC(c3, i + 3);
        if (i + 4 < cnt) PROC(c4, i + 4);
        if (i + 5 < cnt) PROC(c5, i + 5);
        if (i + 6 < cnt) PROC(c6, i + 6);
        if (i + 7 < cnt) PROC(c7, i + 7);
      }
    }
    float inv = 1.f / (den + 1e-16f);
    float oo0 = acc0 * inv, oo1 = acc1 * inv;
    float2 xr2 = *reinterpret_cast<const float2*>(xr + (size_t)node * D + d0);
    float2 x2 = *reinterpret_cast<const float2*>(x + (size_t)node * D + d0);
    float pb = oo0 * wb0.x + xr2.x * wb1.x + (oo0 - xr2.x) * wb2.x
             + oo1 * wb0.y + xr2.y * wb1.y + (oo1 - xr2.y) * wb2.y;
#pragma unroll
    for (int msk = 1; msk < 64; msk <<= 1) pb += __shfl_xor(pb, msk, 64);
    float beta = 1.f / (1.f + __expf(-pb));
    float h0 = x2.x + beta * xr2.x + (1.f - beta) * oo0;
    float h1 = x2.y + beta * xr2.y + (1.f - beta) * oo1;
    *reinterpret_cast<float2*>(h + (size_t)node * D + d0) = make_float2(h0, h1);
    s_h0 += h0; s_h20 += h0 * h0;
    s_h1 += h1; s_h21 += h1 * h1;
  }
  rs_h[wid * D + d0] = s_h0;   rs_h[wid * D + d0 + 1] = s_h1;
  rs_h2[wid * D + d0] = s_h20; rs_h2[wid * D + d0 + 1] = s_h21;
  __syncthreads();
  if (threadIdx.x < D) {
    int d = threadIdx.x;
    float sh = rs_h[d] + rs_h[D + d] + rs_h[2 * D + d] + rs_h[3 * D + d];
    float sh2 = rs_h2[d] + rs_h2[D + d] + rs_h2[2 * D + d] + rs_h2[3 * D + d];
    atomicAdd(&sums[d], sh);
    atomicAdd(&sums[D + d], sh2);
  }
}

// ---------------- kernel 5: fused GraphNorm-stats + FFN, LDS-staged ----------------
__global__ __launch_bounds__(256) void ffn_fused(
    const float* __restrict__ h, const float* __restrict__ sums,
    const float* __restrict__ gn_w, const float* __restrict__ gn_b,
    const float* __restrict__ gn_ms,
    const ushort* __restrict__ W1t, const float* __restrict__ b1,
    const ushort* __restrict__ W2t, const float* __restrict__ b2,
    float* __restrict__ out, float inv_n, int n) {
  __shared__ ushort xa[32 * XPAD];
  __shared__ ushort tt[32 * TPAD];
  __shared__ float scsh[2 * D];
  if (threadIdx.x < D) {
    int d = threadIdx.x;
    float mean = sums[d] * inv_n;
    float ex2 = sums[D + d] * inv_n;
    float ms = gn_ms[d];
    float var = ex2 - 2.f * ms * mean * mean + ms * ms * mean * mean;
    float inv = 1.f / sqrtf(var + 1e-5f);
    float scale = gn_w[d] * inv;
    scsh[d] = scale;
    scsh[D + d] = gn_b[d] - ms * mean * scale;
  }
  __syncthreads();
  int r0 = blockIdx.x * 32;
  {
    int row = threadIdx.x >> 3;
    int seg = threadIdx.x & 7;
    int grow = min(r0 + row, n - 1);
    const float4* p = reinterpret_cast<const float4*>(h + (size_t)grow * D + seg * 16);
    float4 f0 = p[0], f1 = p[1], f2 = p[2], f3 = p[3];
    const float4* sc = reinterpret_cast<const float4*>(scsh + seg * 16);
    const float4* sh = reinterpret_cast<const float4*>(scsh + D + seg * 16);
    float4 s0 = sc[0], s1 = sc[1], s2 = sc[2], s3 = sc[3];
    float4 t0 = sh[0], t1 = sh[1], t2 = sh[2], t3 = sh[3];
    bf16x8 u0, u1;
    u0[0] = (short)f2bf(f0.x * s0.x + t0.x); u0[1] = (short)f2bf(f0.y * s0.y + t0.y);
    u0[2] = (short)f2bf(f0.z * s0.z + t0.z); u0[3] = (short)f2bf(f0.w * s0.w + t0.w);
    u0[4] = (short)f2bf(f1.x * s1.x + t1.x); u0[5] = (short)f2bf(f1.y * s1.y + t1.y);
    u0[6] = (short)f2bf(f1.z * s1.z + t1.z); u0[7] = (short)f2bf(f1.w * s1.w + t1.w);
    u1[0] = (short)f2bf(f2.x * s2.x + t2.x); u1[1] = (short)f2bf(f2.y * s2.y + t2.y);
    u1[2] = (short)f2bf(f2.z * s2.z + t2.z); u1[3] = (short)f2bf(f2.w * s2.w + t2.w);
    u1[4] = (short)f2bf(f3.x * s3.x + t3.x); u1[5] = (short)f2bf(f3.y * s3.y + t3.y);
    u1[6] = (short)f2bf(f3.z * s3.z + t3.z); u1[7] = (short)f2bf(f3.w * s3.w + t3.w);
    ushort* dl = xa + row * XPAD + seg * 16;
    *reinterpret_cast<bf16x8*>(dl) = u0;
    *reinterpret_cast<bf16x8*>(dl + 8) = u1;
  }
  __syncthreads();
  int wv = threadIdx.x >> 6;
  int l = threadIdx.x & 63;
  int lr = l & 15, lg = l >> 4;
  int c0 = wv * 128;
  {
    f32x4 acc[2][8];
#pragma unroll
    for (int m = 0; m < 2; ++m)
#pragma unroll
      for (int nn = 0; nn < 8; ++nn) acc[m][nn] = (f32x4)0.f;
#pragma unroll
    for (int kb = 0; kb < 4; ++kb) {
      int k0 = kb * 32 + lg * 8;
      bf16x8 a[2];
#pragma unroll
      for (int m = 0; m < 2; ++m)
        a[m] = *reinterpret_cast<const bf16x8*>(xa + (m * 16 + lr) * XPAD + k0);
      bf16x8 b[8];
#pragma unroll
      for (int nn = 0; nn < 8; ++nn)
        b[nn] = *reinterpret_cast<const bf16x8*>(W1t + (c0 + nn * 16 + lr) * D + k0);
#pragma unroll
      for (int m = 0; m < 2; ++m)
#pragma unroll
        for (int nn = 0; nn < 8; ++nn)
          acc[m][nn] = __builtin_amdgcn_mfma_f32_16x16x32_bf16(a[m], b[nn], acc[m][nn], 0, 0, 0);
    }
    const float inv_sqrt2 = 0.70710678118654752440f;
#pragma unroll
    for (int m = 0; m < 2; ++m)
#pragma unroll
      for (int nn = 0; nn < 8; ++nn) {
        int col = c0 + nn * 16 + lr;
        float bb = b1[col];
#pragma unroll
        for (int j = 0; j < 4; ++j) {
          int rowl = m * 16 + lg * 4 + j;
          float val = acc[m][nn][j] + bb;
          val = 0.5f * val * (1.f + erff(val * inv_sqrt2));
          tt[rowl * TPAD + col] = f2bf(val);
        }
      }
  }
  __syncthreads();
  {
    f32x4 acc[2][2];
#pragma unroll
    for (int m = 0; m < 2; ++m)
#pragma unroll
      for (int nn = 0; nn < 2; ++nn) acc[m][nn] = (f32x4)0.f;
#pragma unroll 4
    for (int kb = 0; kb < 16; ++kb) {
      int k0 = kb * 32 + lg * 8;
      bf16x8 a[2];
#pragma unroll
      for (int m = 0; m < 2; ++m)
        a[m] = *reinterpret_cast<const bf16x8*>(tt + (m * 16 + lr) * TPAD + k0);
      bf16x8 b[2];
#pragma unroll
      for (int nn = 0; nn < 2; ++nn)
        b[nn] = *reinterpret_cast<const bf16x8*>(W2t + (wv * 32 + nn * 16 + lr) * FF + k0);
#pragma unroll
      for (int m = 0; m < 2; ++m)
#pragma unroll
        for (int nn = 0; nn < 2; ++nn)
          acc[m][nn] = __builtin_amdgcn_mfma_f32_16x16x32_bf16(a[m], b[nn], acc[m][nn], 0, 0, 0);
    }
#pragma unroll
    for (int m = 0; m < 2; ++m)
#pragma unroll
      for (int nn = 0; nn < 2; ++nn) {
        int col = wv * 32 + nn * 16 + lr;
        float bb = b2[col];
#pragma unroll
        for (int j = 0; j < 4; ++j) {
          int rowl = m * 16 + lg * 4 + j;
          int row = r0 + rowl;
          if (row < n) {
            float hn = bf2f(xa[rowl * XPAD + col]);
            out[(size_t)row * D + col] = hn + acc[m][nn][j] + bb;
          }
        }
      }
  }
}

extern "C" void kernel_launch(void* const* d_in, const int* in_sizes, int n_in,
                              void* d_out, int out_size, void* d_ws, size_t ws_size,
                              hipStream_t stream) {
  const float* x     = (const float*)d_in[0];
  const int*   ei    = (const int*)d_in[1];
  const float* attr  = (const float*)d_in[2];
  const float* Wq    = (const float*)d_in[3];
  const float* bq    = (const float*)d_in[4];
  const float* Wk    = (const float*)d_in[5];
  const float* bk    = (const float*)d_in[6];
  const float* Wv    = (const float*)d_in[7];
  const float* bv    = (const float*)d_in[8];
  const float* We    = (const float*)d_in[9];
  const float* Wskip = (const float*)d_in[10];
  const float* bskip = (const float*)d_in[11];
  const float* Wbeta = (const float*)d_in[12];
  const float* gn_w  = (const float*)d_in[13];
  const float* gn_b  = (const float*)d_in[14];
  const float* gn_ms = (const float*)d_in[15];
  const float* W1    = (const float*)d_in[16];
  const float* b1    = (const float*)d_in[17];
  const float* W2    = (const float*)d_in[18];
  const float* b2    = (const float*)d_in[19];

  const int n = in_sizes[0] / D;
  const int E = in_sizes[1] / 2;
  const int* src = ei;
  const int* dst = ei + E;
  const size_t ND = (size_t)n * D;

  // ---- workspace layout ----
  ushort* qb = (ushort*)d_ws;                  // ND bf16
  unsigned* kvf8 = (unsigned*)(qb + ND);       // n*64 uints (fp8 k/v interleaved)
  float* xr = (float*)(kvf8 + (size_t)n * 64); // ND f32
  int* deg = (int*)(xr + ND);                  // n    (zeroed)
  float* sums = (float*)(deg + n);             // 2D   (zeroed)
  int* off = (int*)(sums + 2 * D);             // n+1
  int* rank = off + n + 1;                     // E
  unsigned* rec = (unsigned*)(rank + E + 1);   // E*8 (32B edge records), 16B-aligned
  rec = (unsigned*)(((size_t)rec + 31) & ~(size_t)31);
  ushort* Wcat_t = (ushort*)(rec + (size_t)E * 8);  // 4*D*D
  ushort* W1t = Wcat_t + 4 * D * D;            // D*FF
  ushort* W2t = W1t + D * FF;                  // FF*D
  float* bcat = (float*)(W2t + FF * D);        // 4D

  (void)hipMemsetAsync(deg, 0, ((size_t)n + 2 * D) * sizeof(int), stream);

  int ghist = (E + 255) / 256;
  prep_hist<<<256 + ghist, 256, 0, stream>>>(Wq, Wk, Wv, Wskip, bq, bk, bv, bskip, W1, W2,
                                             dst, deg, rank, E, Wcat_t, bcat, W1t, W2t);
  scan_kernel<<<1, 1024, 0, stream>>>(deg, off, n);

  int gm = (n + 31) / 32;
  gemm_scatter<<<gm + ghist, 256, 0, stream>>>(x, Wcat_t, bcat, qb, kvf8, xr, n, gm, dst,
                                               src, rank, off, attr, rec, E);

  node_attn<<<2048, 256, 0, stream>>>(rec, off, We, qb, kvf8, xr, x, Wbeta,
                                      (float*)d_out, sums, n);

  ffn_fused<<<(n + 31) / 32, 256, 0, stream>>>((const float*)d_out, sums, gn_w, gn_b, gn_ms,
                                               W1t, b1, W2t, b2, (float*)d_out,
                                               1.f / (float)n, n);
}